// Round 1
// baseline (149.321 us; speedup 1.0000x reference)
//
#include <hip/hip_runtime.h>

// NNUE-style net: h = relu(sum_{i<29} emb[x[r,i]]);  (128)
// h2 = h @ w2.T + b2 (32); c2 = (relu(h2), relu(-h2)) (64)
// h3 = c2 @ w3.T + b3 (32); c3 = (relu(h3), relu(-h3)) (64)
// out = c3 @ w4.T (1)
//
// Block = 256 threads (4 waves), 64 rows/block, grid = 1024.
// LDS: h1 transposed [d=128][r=64] with row-stride 65 (conflict-free phase-2
// reads); region reused for h2 (dims 0..31) and h3 (dims 32..63).

#define STR 65

__device__ __forceinline__ float frelu(float v) { return v > 0.f ? v : 0.f; }

__global__ __launch_bounds__(256, 4) void nnue_fwd(
    const int* __restrict__ x, const float* __restrict__ emb,
    const float* __restrict__ w2, const float* __restrict__ b2,
    const float* __restrict__ w3, const float* __restrict__ b3,
    const float* __restrict__ w4, float* __restrict__ out)
{
    __shared__ float lds[128 * STR];   // 33280 B -> 4 blocks/CU

    const int t    = threadIdx.x;
    const int lane = t & 63;
    const int half = lane >> 5;        // which of the 2 emb rows this iter
    const int sub  = lane & 31;        // float4 slot within a 128-dim row
    const int row0 = blockIdx.x * 64;

    // ---------------- Phase 1: gather + sum, wave-per-row ----------------
    // Each wave handles 16 rows; per iteration the 64 lanes fetch TWO emb
    // rows as coalesced 32xfloat4 (512 B each).
    const int wave = __builtin_amdgcn_readfirstlane(t >> 6);
    for (int rr = 0; rr < 16; ++rr) {
        const int rloc = wave * 16 + rr;
        const int* xr = x + (size_t)(row0 + rloc) * 32;   // wave-uniform -> s_load
        float ax = 0.f, ay = 0.f, az = 0.f, aw = 0.f;
        #pragma unroll
        for (int j = 0; j < 14; ++j) {          // index positions 0..27
            const int ia  = xr[2 * j];
            const int ib  = xr[2 * j + 1];
            const int idx = half ? ib : ia;
            const float4 v = *((const float4*)(emb + (size_t)idx * 128) + sub);
            ax += v.x; ay += v.y; az += v.z; aw += v.w;
        }
        {   // index position 28: only half 0 contributes
            const int ia = xr[28];
            const float4 v = *((const float4*)(emb + (size_t)ia * 128) + sub);
            if (half == 0) { ax += v.x; ay += v.y; az += v.z; aw += v.w; }
        }
        // combine the two halves (lane i += lane i+32)
        ax += __shfl_down(ax, 32, 64);
        ay += __shfl_down(ay, 32, 64);
        az += __shfl_down(az, 32, 64);
        aw += __shfl_down(aw, 32, 64);
        if (half == 0) {   // write relu(h) transposed: lds[d*STR + r]
            lds[(4 * sub + 0) * STR + rloc] = frelu(ax);
            lds[(4 * sub + 1) * STR + rloc] = frelu(ay);
            lds[(4 * sub + 2) * STR + rloc] = frelu(az);
            lds[(4 * sub + 3) * STR + rloc] = frelu(aw);
        }
    }
    __syncthreads();

    // ---------------- Phase 2: dense layers, lane = row ----------------
    const int r  = lane;                                        // row 0..63
    const int ob = __builtin_amdgcn_readfirstlane((t >> 6) * 8); // 8 outputs/wave

    // Layer 2: 128 -> 32. Weights wave-uniform -> scalar loads.
    float a2[8];
    #pragma unroll
    for (int oo = 0; oo < 8; ++oo) a2[oo] = b2[ob + oo];
    #pragma unroll 4
    for (int d = 0; d < 128; ++d) {
        const float hv = lds[d * STR + r];     // 64 consecutive floats: no conflict
        #pragma unroll
        for (int oo = 0; oo < 8; ++oo)
            a2[oo] = fmaf(hv, w2[(ob + oo) * 128 + d], a2[oo]);
    }
    __syncthreads();               // all waves done reading h1
    #pragma unroll
    for (int oo = 0; oo < 8; ++oo) lds[(ob + oo) * STR + r] = a2[oo];  // h2 (pre-act)
    __syncthreads();

    // Layer 3: CReLU(32->64) -> 32
    float a3[8];
    #pragma unroll
    for (int oo = 0; oo < 8; ++oo) a3[oo] = b3[ob + oo];
    #pragma unroll 4
    for (int j = 0; j < 32; ++j) {
        const float v = lds[j * STR + r];
        const float p = frelu(v), n = frelu(-v);
        #pragma unroll
        for (int oo = 0; oo < 8; ++oo)
            a3[oo] = fmaf(p, w3[(ob + oo) * 64 + j],
                     fmaf(n, w3[(ob + oo) * 64 + 32 + j], a3[oo]));
    }
    // h3 region [32*STR, 64*STR) is disjoint from h2 reads -> no barrier needed
    #pragma unroll
    for (int oo = 0; oo < 8; ++oo) lds[32 * STR + (ob + oo) * STR + r] = a3[oo];
    __syncthreads();

    // Layer 4: CReLU(32->64) -> 1, wave 0 only
    if (t < 64) {
        float s = 0.f;
        #pragma unroll 4
        for (int j = 0; j < 32; ++j) {
            const float v = lds[32 * STR + j * STR + t];
            s = fmaf(frelu(v), w4[j], fmaf(frelu(-v), w4[32 + j], s));
        }
        out[row0 + t] = s;
    }
}

extern "C" void kernel_launch(void* const* d_in, const int* in_sizes, int n_in,
                              void* d_out, int out_size, void* d_ws, size_t ws_size,
                              hipStream_t stream) {
    const int*   x   = (const int*)d_in[0];
    const float* emb = (const float*)d_in[1];
    const float* w2  = (const float*)d_in[2];
    const float* b2  = (const float*)d_in[3];
    const float* w3  = (const float*)d_in[4];
    const float* b3  = (const float*)d_in[5];
    const float* w4  = (const float*)d_in[6];
    float* out = (float*)d_out;
    const int n_rows = in_sizes[0] / 32;      // 65536
    dim3 grid(n_rows / 64), block(256);
    hipLaunchKernelGGL(nnue_fwd, grid, block, 0, stream,
                       x, emb, w2, b2, w3, b3, w4, out);
}

// Round 2
// 119.513 us; speedup vs baseline: 1.2494x; 1.2494x over previous
//
#include <hip/hip_runtime.h>
#include <hip/hip_fp16.h>

// NNUE forward. Round 2: fp16 embedding table staged in d_ws (3.8 MB -> fits
// per-XCD 4 MB L2; halves gather bytes & cache lines vs fp32).
//
// h  = relu(sum_{i<29} emb[x[r,i]])        (128)
// h2 = h @ w2.T + b2; c2 = CReLU(h2)       (32 -> 64)
// h3 = c2 @ w3.T + b3; c3 = CReLU(h3)      (32 -> 64)
// out = c3 @ w4.T                          (1)
//
// Main kernel: block = 256 (4 waves), 64 rows/block, grid = 1024.
// Phase 1 gather: 16 lanes per emb row -> 4 rows per wave-load (16 B/lane),
// 8 loads per output row. fp32 accumulation, cross-group reduce via shfl_xor.
// LDS: h1 transposed [dim][row] stride 65 (phase-2 reads conflict-free).

#define STR 65

using h8 = __attribute__((ext_vector_type(8))) _Float16;
using h4 = __attribute__((ext_vector_type(4))) _Float16;

__device__ __forceinline__ float frelu(float v) { return v > 0.f ? v : 0.f; }

// ---- emb fp32 -> fp16 conversion: one float4 per thread, exact-size grid ----
__global__ __launch_bounds__(256) void cvt_emb(const float* __restrict__ emb,
                                               _Float16* __restrict__ tab) {
    const int i = blockIdx.x * 256 + threadIdx.x;       // float4 index
    const float4 v = ((const float4*)emb)[i];
    h4 o;
    o[0] = (_Float16)v.x; o[1] = (_Float16)v.y;
    o[2] = (_Float16)v.z; o[3] = (_Float16)v.w;
    ((h4*)tab)[i] = o;
}

__global__ __launch_bounds__(256, 4) void nnue_fwd(
    const int* __restrict__ x, const _Float16* __restrict__ tab,
    const float* __restrict__ w2, const float* __restrict__ b2,
    const float* __restrict__ w3, const float* __restrict__ b3,
    const float* __restrict__ w4, float* __restrict__ out)
{
    __shared__ float lds[128 * STR];   // 33280 B -> 4 blocks/CU (16 waves)

    const int t    = threadIdx.x;
    const int lane = t & 63;
    const int g    = lane >> 4;        // lane group 0..3: which index position
    const int sub  = lane & 15;        // 8-dim chunk within a 128-dim row
    const int row0 = blockIdx.x * 64;
    const int wave = __builtin_amdgcn_readfirstlane(t >> 6);

    // ---------------- Phase 1: gather + sum ----------------
    for (int rr = 0; rr < 16; ++rr) {
        const int rloc = wave * 16 + rr;
        // one coalesced load of this row's 32 indices; distribute via shfl
        const int xv = x[(size_t)(row0 + rloc) * 32 + (lane & 31)];

        float acc[8] = {0.f, 0.f, 0.f, 0.f, 0.f, 0.f, 0.f, 0.f};
        #pragma unroll
        for (int jj = 0; jj < 7; ++jj) {            // positions 0..27: 4/iter
            const int idx = __shfl(xv, 4 * jj + g, 64);
            const h8 v = *((const h8*)(tab + (size_t)idx * 128) + sub);
            #pragma unroll
            for (int k = 0; k < 8; ++k) acc[k] += (float)v[k];
        }
        {   // position 28: group 0 only
            const int idx = __shfl(xv, 28, 64);
            if (g == 0) {
                const h8 v = *((const h8*)(tab + (size_t)idx * 128) + sub);
                #pragma unroll
                for (int k = 0; k < 8; ++k) acc[k] += (float)v[k];
            }
        }
        // reduce the 4 groups (same sub -> same dims)
        #pragma unroll
        for (int k = 0; k < 8; ++k) {
            acc[k] += __shfl_xor(acc[k], 16, 64);
            acc[k] += __shfl_xor(acc[k], 32, 64);
        }
        // every lane now has the full sum for dims [8*sub, 8*sub+8);
        // spread the 128 stores across all 64 lanes: 2 dims per lane
        const int d0 = 8 * sub + 2 * g;
        lds[(d0 + 0) * STR + rloc] = frelu(acc[2 * g + 0]);
        lds[(d0 + 1) * STR + rloc] = frelu(acc[2 * g + 1]);
    }
    __syncthreads();

    // ---------------- Phase 2: dense layers, lane = row ----------------
    const int r  = lane;                                         // row 0..63
    const int ob = __builtin_amdgcn_readfirstlane((t >> 6) * 8); // 8 outs/wave

    // Layer 2: 128 -> 32 (weights wave-uniform -> scalar loads)
    float a2[8];
    #pragma unroll
    for (int oo = 0; oo < 8; ++oo) a2[oo] = b2[ob + oo];
    #pragma unroll 4
    for (int d = 0; d < 128; ++d) {
        const float hv = lds[d * STR + r];      // 64 consecutive: conflict-free
        #pragma unroll
        for (int oo = 0; oo < 8; ++oo)
            a2[oo] = fmaf(hv, w2[(ob + oo) * 128 + d], a2[oo]);
    }
    __syncthreads();                // all waves done reading h1
    #pragma unroll
    for (int oo = 0; oo < 8; ++oo) lds[(ob + oo) * STR + r] = a2[oo];
    __syncthreads();

    // Layer 3: CReLU(32 -> 64) -> 32
    float a3[8];
    #pragma unroll
    for (int oo = 0; oo < 8; ++oo) a3[oo] = b3[ob + oo];
    #pragma unroll 4
    for (int j = 0; j < 32; ++j) {
        const float v = lds[j * STR + r];
        const float p = frelu(v), n = frelu(-v);
        #pragma unroll
        for (int oo = 0; oo < 8; ++oo)
            a3[oo] = fmaf(p, w3[(ob + oo) * 64 + j],
                     fmaf(n, w3[(ob + oo) * 64 + 32 + j], a3[oo]));
    }
    // h3 goes to lds rows 32..63 — disjoint from h2 reads (rows 0..31)
    #pragma unroll
    for (int oo = 0; oo < 8; ++oo) lds[(32 + ob + oo) * STR + r] = a3[oo];
    __syncthreads();

    // Layer 4: CReLU(32 -> 64) -> 1, wave 0 only
    if (t < 64) {
        float s = 0.f;
        #pragma unroll 4
        for (int j = 0; j < 32; ++j) {
            const float v = lds[(32 + j) * STR + t];
            s = fmaf(frelu(v), w4[j], fmaf(frelu(-v), w4[32 + j], s));
        }
        out[row0 + t] = s;
    }
}

extern "C" void kernel_launch(void* const* d_in, const int* in_sizes, int n_in,
                              void* d_out, int out_size, void* d_ws, size_t ws_size,
                              hipStream_t stream) {
    const int*   x   = (const int*)d_in[0];
    const float* emb = (const float*)d_in[1];
    const float* w2  = (const float*)d_in[2];
    const float* b2  = (const float*)d_in[3];
    const float* w3  = (const float*)d_in[4];
    const float* b3  = (const float*)d_in[5];
    const float* w4  = (const float*)d_in[6];
    float* out = (float*)d_out;

    _Float16* tab = (_Float16*)d_ws;            // needs 14848*128*2 = 3.8 MB

    const int emb_elems = in_sizes[1];          // 14848*128 = 1,900,544
    const int n_rows    = in_sizes[0] / 32;     // 65536

    // stage fp16 table (runs every call; ~2 us)
    hipLaunchKernelGGL(cvt_emb, dim3(emb_elems / 4 / 256), dim3(256), 0, stream,
                       emb, tab);
    hipLaunchKernelGGL(nnue_fwd, dim3(n_rows / 64), dim3(256), 0, stream,
                       x, tab, w2, b2, w3, b3, w4, out);
}

// Round 3
// 106.388 us; speedup vs baseline: 1.4035x; 1.1234x over previous
//
#include <hip/hip_runtime.h>
#include <hip/hip_fp16.h>

// NNUE forward, round 3.
//  - fp16 emb table staged in d_ws (L2-resident, 3.8 MB)
//  - phase 1: 4 rows per wave iteration (lane-group = row), packed v_pk_add_f16
//    accumulation (2 banks), relu'd fp16 pairs straight to LDS
//  - phase 2: v_dot2_f32_f16 against fp16-packed weights (prepacked in d_ws),
//    fp32 accumulators
// Block = 256 (4 waves), 64 rows/block, grid = 1024.

#define STR 65   // LDS row stride in h2 elements (odd -> conflict-free)

using h2  = _Float16 __attribute__((ext_vector_type(2)));
using h4  = _Float16 __attribute__((ext_vector_type(4)));
using h8v = _Float16 __attribute__((ext_vector_type(8)));

union H8 { h8v v; h2 h[4]; };

__device__ __forceinline__ float frelu(float v) { return v > 0.f ? v : 0.f; }

__device__ __forceinline__ h2 h2relu(h2 v) {
    h2 r;
    r[0] = v[0] > (_Float16)0 ? v[0] : (_Float16)0;
    r[1] = v[1] > (_Float16)0 ? v[1] : (_Float16)0;
    return r;
}

// ---- emb fp32 -> fp16 (one float4 / thread, exact-size grid) ----
__global__ __launch_bounds__(256) void cvt_emb(const float* __restrict__ emb,
                                               _Float16* __restrict__ tab) {
    const int i = blockIdx.x * 256 + threadIdx.x;
    const float4 v = ((const float4*)emb)[i];
    h4 o;
    o[0] = (_Float16)v.x; o[1] = (_Float16)v.y;
    o[2] = (_Float16)v.z; o[3] = (_Float16)v.w;
    ((h4*)tab)[i] = o;
}

// ---- weight prepack: w2 flat fp16; w3/w4 interleaved (w[o][j], w[o][32+j]) ----
__global__ __launch_bounds__(256) void prep_w(
    const float* __restrict__ w2, const float* __restrict__ w3,
    const float* __restrict__ w4,
    _Float16* __restrict__ w2p, h2* __restrict__ w3p, h2* __restrict__ w4p) {
    const int i = threadIdx.x;
    for (int e = i; e < 32 * 128; e += 256) w2p[e] = (_Float16)w2[e];
    for (int p = i; p < 32 * 32; p += 256) {
        const int o = p >> 5, j = p & 31;
        h2 c; c[0] = (_Float16)w3[o * 64 + j]; c[1] = (_Float16)w3[o * 64 + 32 + j];
        w3p[p] = c;
    }
    if (i < 32) {
        h2 c; c[0] = (_Float16)w4[i]; c[1] = (_Float16)w4[32 + i];
        w4p[i] = c;
    }
}

__global__ __launch_bounds__(256, 4) void nnue_fwd(
    const int* __restrict__ x, const _Float16* __restrict__ tab,
    const h2* __restrict__ w2p, const float* __restrict__ b2,
    const h2* __restrict__ w3p, const float* __restrict__ b3,
    const h2* __restrict__ w4p, float* __restrict__ out)
{
    __shared__ h2 lds[64 * STR];   // 16640 B; h1 pairs, reused for c2/c3

    const int t    = threadIdx.x;
    const int lane = t & 63;
    const int g    = lane >> 4;        // lane group = which of 4 rows
    const int sub  = lane & 15;        // 8-dim (4-pair) chunk within a row
    const int row0 = blockIdx.x * 64;
    const int wave = __builtin_amdgcn_readfirstlane(t >> 6);

    // ---------------- Phase 1: gather + packed fp16 sum ----------------
    for (int it = 0; it < 4; ++it) {
        const int rb = wave * 16 + it * 4;               // block-local base row
        // indices for my group's row: positions 0..15 and 16..31 (28 used)
        const int xv0 = x[(size_t)(row0 + rb + g) * 32 + sub];
        const int xv1 = x[(size_t)(row0 + rb + g) * 32 + 16 + sub];

        h2 accA[4] = {}, accB[4] = {};
        #pragma unroll
        for (int j = 0; j < 29; ++j) {
            const int src = (lane & 48) | (j & 15);      // lane g*16 + (j%16)
            const int idx = __shfl((j < 16) ? xv0 : xv1, src, 64);
            H8 u;
            u.v = *(const h8v*)((const char*)tab +
                                (((unsigned)idx) << 8) + (sub << 4));
            if (j & 1) {
                accB[0] += u.h[0]; accB[1] += u.h[1];
                accB[2] += u.h[2]; accB[3] += u.h[3];
            } else {
                accA[0] += u.h[0]; accA[1] += u.h[1];
                accA[2] += u.h[2]; accA[3] += u.h[3];
            }
        }
        #pragma unroll
        for (int k = 0; k < 4; ++k) {
            const h2 s = h2relu(accA[k] + accB[k]);
            lds[(4 * sub + k) * STR + rb + g] = s;       // [pair-dim][row]
        }
    }
    __syncthreads();

    // ---------------- Phase 2: dense layers, lane = row ----------------
    const int r  = lane;
    const int ob = __builtin_amdgcn_readfirstlane((t >> 6) * 8); // 8 outs/wave

    // Layer 2: 128 -> 32 via dot2 over 64 fp16 pairs
    float a2[8];
    #pragma unroll
    for (int oo = 0; oo < 8; ++oo) a2[oo] = b2[ob + oo];
    #pragma unroll 8
    for (int pd = 0; pd < 64; ++pd) {
        const h2 hp = lds[pd * STR + r];                 // conflict-free
        #pragma unroll
        for (int oo = 0; oo < 8; ++oo)
            a2[oo] = __builtin_amdgcn_fdot2(hp, w2p[(ob + oo) * 64 + pd],
                                            a2[oo], false);
    }
    __syncthreads();               // all waves done reading h1
    #pragma unroll
    for (int oo = 0; oo < 8; ++oo) {
        h2 c; c[0] = (_Float16)frelu(a2[oo]); c[1] = (_Float16)frelu(-a2[oo]);
        lds[(ob + oo) * STR + r] = c;                    // c2: rows 0..31
    }
    __syncthreads();

    // Layer 3: CReLU(32->64) -> 32 via dot2 on (p,n) pairs
    float a3[8];
    #pragma unroll
    for (int oo = 0; oo < 8; ++oo) a3[oo] = b3[ob + oo];
    #pragma unroll 8
    for (int j = 0; j < 32; ++j) {
        const h2 cp = lds[j * STR + r];
        #pragma unroll
        for (int oo = 0; oo < 8; ++oo)
            a3[oo] = __builtin_amdgcn_fdot2(cp, w3p[(ob + oo) * 32 + j],
                                            a3[oo], false);
    }
    // c3 -> rows 32..63 (disjoint from c2 reads; h1 reads already barriered)
    #pragma unroll
    for (int oo = 0; oo < 8; ++oo) {
        h2 c; c[0] = (_Float16)frelu(a3[oo]); c[1] = (_Float16)frelu(-a3[oo]);
        lds[(32 + ob + oo) * STR + r] = c;
    }
    __syncthreads();

    // Layer 4: 64 -> 1, wave 0 only
    if (t < 64) {
        float s = 0.f;
        #pragma unroll
        for (int j = 0; j < 32; ++j)
            s = __builtin_amdgcn_fdot2(lds[(32 + j) * STR + t], w4p[j], s, false);
        out[row0 + t] = s;
    }
}

extern "C" void kernel_launch(void* const* d_in, const int* in_sizes, int n_in,
                              void* d_out, int out_size, void* d_ws, size_t ws_size,
                              hipStream_t stream) {
    const int*   x   = (const int*)d_in[0];
    const float* emb = (const float*)d_in[1];
    const float* w2  = (const float*)d_in[2];
    const float* b2  = (const float*)d_in[3];
    const float* w3  = (const float*)d_in[4];
    const float* b3  = (const float*)d_in[5];
    const float* w4  = (const float*)d_in[6];
    float* out = (float*)d_out;

    const int emb_elems = in_sizes[1];          // 1,900,544
    const int n_rows    = in_sizes[0] / 32;     // 65536

    char* ws = (char*)d_ws;
    _Float16* tab = (_Float16*)ws;                       // 3,801,088 B
    _Float16* w2p = (_Float16*)(ws + 3801088);           // 8,192 B
    h2*       w3p = (h2*)(ws + 3801088 + 8192);          // 4,096 B
    h2*       w4p = (h2*)(ws + 3801088 + 8192 + 4096);   // 128 B

    hipLaunchKernelGGL(cvt_emb, dim3(emb_elems / 4 / 256), dim3(256), 0, stream,
                       emb, tab);
    hipLaunchKernelGGL(prep_w, dim3(1), dim3(256), 0, stream,
                       w2, w3, w4, w2p, w3p, w4p);
    hipLaunchKernelGGL(nnue_fwd, dim3(n_rows / 64), dim3(256), 0, stream,
                       x, tab, (const h2*)w2p, b2, w3p, b3, w4p, out);
}

// Round 4
// 105.464 us; speedup vs baseline: 1.4159x; 1.0088x over previous
//
#include <hip/hip_runtime.h>
#include <hip/hip_fp16.h>

// NNUE forward, round 4.
//  - fp16 emb table staged in d_ws (L2-resident, 3.8 MB)
//  - 32 rows/block, grid 2048 -> 8 blocks/CU = 32 waves/CU (double round-3 TLP
//    to hide L2 gather latency; round 3 was grid-limited to 16 waves/CU)
//  - phase 1: 4 rows per wave iteration (lane-group = row), packed v_pk_add_f16
//  - phase 2: wave-halves compute redundantly (keeps weight indexing
//    wave-uniform -> scalar loads); v_dot2_f32_f16 with fp32 accumulators
// LDS: h1 pairs [pd=64][row 32, stride 33] = 8448 B.

#define STR2 33

using h2  = _Float16 __attribute__((ext_vector_type(2)));
using h4  = _Float16 __attribute__((ext_vector_type(4)));
using h8v = _Float16 __attribute__((ext_vector_type(8)));

union H8 { h8v v; h2 h[4]; };

__device__ __forceinline__ float frelu(float v) { return v > 0.f ? v : 0.f; }

__device__ __forceinline__ h2 h2relu(h2 v) {
    h2 r;
    r[0] = v[0] > (_Float16)0 ? v[0] : (_Float16)0;
    r[1] = v[1] > (_Float16)0 ? v[1] : (_Float16)0;
    return r;
}

// ---- staging: fp32->fp16 table; last block packs the weights ----
__global__ __launch_bounds__(256) void stage(
    const float* __restrict__ emb, _Float16* __restrict__ tab,
    const float* __restrict__ w2, const float* __restrict__ w3,
    const float* __restrict__ w4,
    _Float16* __restrict__ w2p, h2* __restrict__ w3p, h2* __restrict__ w4p,
    int n4) {
    if ((int)blockIdx.x == (int)gridDim.x - 1) {
        const int i = threadIdx.x;
        for (int e = i; e < 32 * 128; e += 256) w2p[e] = (_Float16)w2[e];
        for (int p = i; p < 32 * 32; p += 256) {
            const int o = p >> 5, j = p & 31;
            h2 c; c[0] = (_Float16)w3[o * 64 + j];
            c[1] = (_Float16)w3[o * 64 + 32 + j];
            w3p[p] = c;
        }
        if (i < 32) {
            h2 c; c[0] = (_Float16)w4[i]; c[1] = (_Float16)w4[32 + i];
            w4p[i] = c;
        }
        return;
    }
    const int i = blockIdx.x * 256 + threadIdx.x;   // float4 index, i < n4
    const float4 v = ((const float4*)emb)[i];
    h4 o;
    o[0] = (_Float16)v.x; o[1] = (_Float16)v.y;
    o[2] = (_Float16)v.z; o[3] = (_Float16)v.w;
    ((h4*)tab)[i] = o;
}

__global__ __launch_bounds__(256, 8) void nnue_fwd(
    const int* __restrict__ x, const _Float16* __restrict__ tab,
    const h2* __restrict__ w2p, const float* __restrict__ b2,
    const h2* __restrict__ w3p, const float* __restrict__ b3,
    const h2* __restrict__ w4p, float* __restrict__ out)
{
    __shared__ h2 lds[64 * STR2];   // 8448 B -> 8 blocks/CU

    const int t    = threadIdx.x;
    const int lane = t & 63;
    const int g    = lane >> 4;        // lane group = which of 4 rows
    const int sub  = lane & 15;        // 8-dim (4-pair) chunk within a row
    const int row0 = blockIdx.x * 32;
    const int wave = __builtin_amdgcn_readfirstlane(t >> 6);

    // ---------------- Phase 1: gather + packed fp16 sum ----------------
    // wave handles rows [wave*8, wave*8+8): 2 iterations of 4 rows
    #pragma unroll
    for (int it = 0; it < 2; ++it) {
        const int rb = wave * 8 + it * 4;            // block-local base row
        const int xv0 = x[(size_t)(row0 + rb + g) * 32 + sub];
        const int xv1 = x[(size_t)(row0 + rb + g) * 32 + 16 + sub];

        h2 accA[4] = {}, accB[4] = {};
        #pragma unroll
        for (int j = 0; j < 29; ++j) {
            const int src = (lane & 48) | (j & 15);  // lane g*16 + (j%16)
            const int idx = __shfl((j < 16) ? xv0 : xv1, src, 64);
            H8 u;
            u.v = *(const h8v*)((const char*)tab +
                                (((unsigned)idx) << 8) + (sub << 4));
            if (j & 1) {
                accB[0] += u.h[0]; accB[1] += u.h[1];
                accB[2] += u.h[2]; accB[3] += u.h[3];
            } else {
                accA[0] += u.h[0]; accA[1] += u.h[1];
                accA[2] += u.h[2]; accA[3] += u.h[3];
            }
        }
        #pragma unroll
        for (int k = 0; k < 4; ++k) {
            const h2 s = h2relu(accA[k] + accB[k]);
            lds[(4 * sub + k) * STR2 + rb + g] = s;  // [pair-dim][row]
        }
    }
    __syncthreads();

    // ---------------- Phase 2: dense layers ----------------
    // lane = row mod 32; both wave-halves compute the same 8 wave-uniform
    // outputs (redundant) so weight loads stay scalar; LDS reads broadcast.
    const int r  = lane & 31;
    const int hf = lane >> 5;
    const int ob = __builtin_amdgcn_readfirstlane((t >> 6) * 8); // 8 outs/wave

    // Layer 2: 128 -> 32 via dot2 over 64 fp16 pairs
    float a2[8];
    #pragma unroll
    for (int oo = 0; oo < 8; ++oo) a2[oo] = b2[ob + oo];
    #pragma unroll 8
    for (int pd = 0; pd < 64; ++pd) {
        const h2 hp = lds[pd * STR2 + r];
        #pragma unroll
        for (int oo = 0; oo < 8; ++oo)
            a2[oo] = __builtin_amdgcn_fdot2(hp, w2p[(ob + oo) * 64 + pd],
                                            a2[oo], false);
    }
    __syncthreads();               // all waves done reading h1
    if (hf == 0) {
        #pragma unroll
        for (int oo = 0; oo < 8; ++oo) {
            h2 c; c[0] = (_Float16)frelu(a2[oo]); c[1] = (_Float16)frelu(-a2[oo]);
            lds[(ob + oo) * STR2 + r] = c;           // c2: pd rows 0..31
        }
    }
    __syncthreads();

    // Layer 3: CReLU(32->64) -> 32 via dot2 on (p,n) pairs
    float a3[8];
    #pragma unroll
    for (int oo = 0; oo < 8; ++oo) a3[oo] = b3[ob + oo];
    #pragma unroll 8
    for (int j = 0; j < 32; ++j) {
        const h2 cp = lds[j * STR2 + r];
        #pragma unroll
        for (int oo = 0; oo < 8; ++oo)
            a3[oo] = __builtin_amdgcn_fdot2(cp, w3p[(ob + oo) * 32 + j],
                                            a3[oo], false);
    }
    // c3 -> pd rows 32..63 (disjoint from c2 reads)
    if (hf == 0) {
        #pragma unroll
        for (int oo = 0; oo < 8; ++oo) {
            h2 c; c[0] = (_Float16)frelu(a3[oo]); c[1] = (_Float16)frelu(-a3[oo]);
            lds[(32 + ob + oo) * STR2 + r] = c;
        }
    }
    __syncthreads();

    // Layer 4: 64 -> 1, lanes 0..31 of wave 0
    if (t < 32) {
        float s = 0.f;
        #pragma unroll
        for (int j = 0; j < 32; ++j)
            s = __builtin_amdgcn_fdot2(lds[(32 + j) * STR2 + t], w4p[j], s, false);
        out[row0 + t] = s;
    }
}

extern "C" void kernel_launch(void* const* d_in, const int* in_sizes, int n_in,
                              void* d_out, int out_size, void* d_ws, size_t ws_size,
                              hipStream_t stream) {
    const int*   x   = (const int*)d_in[0];
    const float* emb = (const float*)d_in[1];
    const float* w2  = (const float*)d_in[2];
    const float* b2  = (const float*)d_in[3];
    const float* w3  = (const float*)d_in[4];
    const float* b3  = (const float*)d_in[5];
    const float* w4  = (const float*)d_in[6];
    float* out = (float*)d_out;

    const int emb_elems = in_sizes[1];          // 1,900,544
    const int n_rows    = in_sizes[0] / 32;     // 65536
    const int n4        = emb_elems / 4;        // 475,136 = 1856*256

    char* ws = (char*)d_ws;
    _Float16* tab = (_Float16*)ws;                       // 3,801,088 B
    _Float16* w2p = (_Float16*)(ws + 3801088);           // 8,192 B
    h2*       w3p = (h2*)(ws + 3801088 + 8192);          // 4,096 B
    h2*       w4p = (h2*)(ws + 3801088 + 8192 + 4096);   // 128 B

    hipLaunchKernelGGL(stage, dim3(n4 / 256 + 1), dim3(256), 0, stream,
                       emb, tab, w2, w3, w4, w2p, w3p, w4p, n4);
    hipLaunchKernelGGL(nnue_fwd, dim3(n_rows / 32), dim3(256), 0, stream,
                       x, tab, (const h2*)w2p, b2, w3p, b3, w4p, out);
}